// Round 9
// baseline (563.383 us; speedup 1.0000x reference)
//
#include <hip/hip_runtime.h>

#define NN 50000
#define EE 800000
#define IND 128
#define EDD 32
#define ODD 16
#define NH 4
#define HD 64
#define NEG_SLOPE 0.2f
#define NBLK ((NN + 255) / 256)   // 196 scan blocks

typedef unsigned int u32;
typedef unsigned short u16;

__device__ __forceinline__ float bf2f(u32 u) { return __uint_as_float(u << 16); }
__device__ __forceinline__ u16 f2bf(float f) {           // round-to-nearest-even
    u32 b = __float_as_uint(f);
    return (u16)((b + 0x7FFF + ((b >> 16) & 1)) >> 16);
}

// ---------------- init+prep fused: deg=0; Wt transpose; w_ee fold ----------
__global__ __launch_bounds__(256)
void k_init_prep(int* __restrict__ deg, const float* __restrict__ W_fc,
                 const float* __restrict__ W_edge, const float* __restrict__ attn_e,
                 float* __restrict__ Wt, float* __restrict__ w_ee) {
    int i = blockIdx.x * 256 + threadIdx.x;
    if (i < NN) deg[i] = 0;
    if (i < HD * IND) {
        int k = i >> 6, j = i & 63;
        Wt[i] = W_fc[j * IND + k];
    }
    if (i < NH * EDD) {
        int h = i >> 5, k = i & 31;
        float s = 0.f;
        for (int d = 0; d < ODD; ++d)
            s += W_edge[(h * ODD + d) * EDD + k] * attn_e[h * ODD + d];
        w_ee[i] = s;
    }
}

// ------- node projection: gridDim.y=2 halves (block-uniform -> s_load weights)
// ------- full feat row prefetched; feat_ written as bf16 (1 row = 1 line) ---
__global__ __launch_bounds__(256)
void k_node(const float* __restrict__ feat, const float* __restrict__ Wt,
            const float* __restrict__ attn_h, const float* __restrict__ attn_t,
            u16* __restrict__ feat_bf, float2* __restrict__ eh2,
            float2* __restrict__ et2) {
    int n = blockIdx.x * 256 + threadIdx.x;
    int half = blockIdx.y;                  // block-uniform -> scalar weight loads
    if (n >= NN) return;
    const int jbase = half * 32;
    float4 row[32];
    const float4* fr4 = (const float4*)(feat + (long)n * IND);
#pragma unroll
    for (int q = 0; q < 32; ++q) row[q] = fr4[q];
    asm volatile("" ::: "memory");          // keep all 32 loads hoisted
    float acc[32];
#pragma unroll
    for (int j = 0; j < 32; ++j) acc[j] = 0.f;
#pragma unroll
    for (int k0 = 0; k0 < 32; ++k0) {
        float f[4] = {row[k0].x, row[k0].y, row[k0].z, row[k0].w};
#pragma unroll
        for (int kk = 0; kk < 4; ++kk) {
            const float* w = Wt + (k0 * 4 + kk) * HD + jbase;  // wave-uniform
#pragma unroll
            for (int j = 0; j < 32; ++j) acc[j] += f[kk] * w[j];
        }
    }
    // pack 32 floats -> 16 u32 (bf16 pairs), write 4x uint4
    u32 pk[16];
#pragma unroll
    for (int q = 0; q < 16; ++q)
        pk[q] = (u32)f2bf(acc[q * 2]) | ((u32)f2bf(acc[q * 2 + 1]) << 16);
    uint4* d4 = (uint4*)((u32*)(feat_bf + (long)n * HD + jbase));
#pragma unroll
    for (int q = 0; q < 4; ++q)
        d4[q] = make_uint4(pk[q*4], pk[q*4+1], pk[q*4+2], pk[q*4+3]);
    float sh[2], st[2];
#pragma unroll
    for (int hh = 0; hh < 2; ++hh) {
        sh[hh] = 0.f; st[hh] = 0.f;
        int hg = half * 2 + hh;
#pragma unroll
        for (int d = 0; d < ODD; ++d) {
            float av = acc[hh * ODD + d];
            sh[hh] += av * attn_h[hg * ODD + d];
            st[hh] += av * attn_t[hg * ODD + d];
        }
    }
    eh2[n * 2 + half] = make_float2(sh[0], sh[1]);
    et2[n * 2 + half] = make_float2(st[0], st[1]);
}

// ---------------- histogram of dst + per-edge rank --------------------------
__global__ __launch_bounds__(256)
void k_hist(const int* __restrict__ dst, int* __restrict__ deg, int* __restrict__ rank) {
    int e = blockIdx.x * 256 + threadIdx.x;
    if (e < EE) rank[e] = atomicAdd(&deg[dst[e]], 1);
}

// ---------------- two-level exclusive scan of deg -> offs -------------------
__global__ __launch_bounds__(256)
void k_scan1(const int* __restrict__ deg, int* __restrict__ offs, int* __restrict__ part) {
    __shared__ int s[256];
    int t = threadIdx.x, i = blockIdx.x * 256 + t;
    int v = (i < NN) ? deg[i] : 0;
    s[t] = v;
    __syncthreads();
#pragma unroll
    for (int o = 1; o < 256; o <<= 1) {
        int u = (t >= o) ? s[t - o] : 0;
        __syncthreads();
        if (t >= o) s[t] += u;
        __syncthreads();
    }
    if (i < NN) offs[i] = s[t] - v;
    if (t == 255) part[blockIdx.x] = s[255];
}

__global__ __launch_bounds__(256)
void k_scan2(int* __restrict__ part) {
    __shared__ int s[256];
    int t = threadIdx.x;
    int v = (t < NBLK) ? part[t] : 0;
    s[t] = v;
    __syncthreads();
#pragma unroll
    for (int o = 1; o < 256; o <<= 1) {
        int u = (t >= o) ? s[t - o] : 0;
        __syncthreads();
        if (t >= o) s[t] += u;
        __syncthreads();
    }
    if (t < NBLK) part[t] = s[t] - v;
}

__global__ __launch_bounds__(256)
void k_scan3(int* __restrict__ offs, const int* __restrict__ part) {
    int i = blockIdx.x * 256 + threadIdx.x;
    if (i < NN) offs[i] += part[i >> 8];
}

// ---------------- perm scatter: the only scattered write --------------------
__global__ __launch_bounds__(256)
void k_perm(const int* __restrict__ dst, const int* __restrict__ rank,
            const int* __restrict__ offs, int* __restrict__ perm) {
    int e = blockIdx.x * 256 + threadIdx.x;
    if (e < EE) perm[offs[dst[e]] + rank[e]] = e;
}

// ------- attention in pos-order: a4[pos]=exp(lrelu(ee+eh[src]+et[dst])) -----
// ------- edge_attr row gather = exactly one 128B line; writes coalesced -----
__global__ __launch_bounds__(256)
void k_att(const float* __restrict__ edge_attr, const int* __restrict__ src,
           const int* __restrict__ dst, const float* __restrict__ w_ee,
           const float4* __restrict__ eh4, const float4* __restrict__ et4,
           const int* __restrict__ perm, float4* __restrict__ a4,
           int* __restrict__ ssrc) {
    int pos = blockIdx.x * 256 + threadIdx.x;
    if (pos >= EE) return;
    int e = perm[pos];                       // coalesced
    int s_ = src[e], d_ = dst[e];            // random 4B, 3.2MB arrays (L2-hot)
    float4 vh = eh4[s_];                     // random 16B, 800KB (L2-hot)
    float4 vt = et4[d_];
    const float4* ea = (const float4*)(edge_attr + (long)e * EDD);
    float4 r[8];
#pragma unroll
    for (int c = 0; c < 8; ++c) r[c] = ea[c];   // one 128B line, 8 reads
    asm volatile("" ::: "memory");
    const float* f = (const float*)r;
    float x[NH];
#pragma unroll
    for (int h = 0; h < NH; ++h) {
        float s = 0.f;
#pragma unroll
        for (int k = 0; k < EDD; ++k) s += f[k] * w_ee[h * EDD + k];  // s_load
        x[h] = s;
    }
    x[0] += vh.x + vt.x; x[1] += vh.y + vt.y;
    x[2] += vh.z + vt.z; x[3] += vh.w + vt.w;
#pragma unroll
    for (int h = 0; h < NH; ++h) {
        float v = x[h];
        v = v > 0.f ? v : NEG_SLOPE * v;
        x[h] = __expf(v);    // no max-shift: logits are 0.1-scale, fp32-safe
    }
    a4[pos] = make_float4(x[0], x[1], x[2], x[3]);   // coalesced
    ssrc[pos] = s_;                                  // coalesced
}

// ------- per-dst reduce: all-coalesced a/ssrc + bf16 feat row gathers -------
__global__ __launch_bounds__(256)
void k_reduce(const int* __restrict__ offs, const int* __restrict__ deg,
              const float* __restrict__ a_flat, const int* __restrict__ ssrc,
              const u16* __restrict__ feat_bf, const float* __restrict__ bias,
              float* __restrict__ out) {
    int wid = (blockIdx.x * 256 + threadIdx.x) >> 6;   // one wave per dst node
    int lane = threadIdx.x & 63;
    if (wid >= NN) return;
    int start = __builtin_amdgcn_readfirstlane(offs[wid]);
    int dn    = __builtin_amdgcn_readfirstlane(deg[wid]);
    int h = lane >> 4;          // head of this lane
    int q = lane & 15;          // edge slot within chunk
    float acc = 0.f, l = 0.f;

    for (int c0 = 0; c0 < dn; c0 += 16) {
        int rem = dn - c0; if (rem > 16) rem = 16;
        // coalesced a read: 64 lanes cover 16 pos x 4 heads (256B)
        float av = (lane < rem * 4) ? a_flat[(start + c0) * 4 + lane] : 0.f;
        float a_q = __shfl(av, 4 * (lane & 15) + (lane >> 4));  // (q,h) redistribute
        if (q >= rem) a_q = 0.f;
        // coalesced ssrc read (16 ints, broadcast x4)
        int qq = (q < rem) ? q : (rem - 1);
        int s_q = ssrc[start + c0 + qq];
        // 16 bf16 feat row gathers (1 line each) issued before consume
        u32 uf[16];
#pragma unroll
        for (int i = 0; i < 16; ++i) {
            int si = __shfl(s_q, i);                   // edge i's src (quad 0)
            uf[i] = feat_bf[(long)si * HD + lane];     // 128B line per edge
        }
#pragma unroll
        for (int i = 0; i < 16; ++i) {
            float ai = __shfl(a_q, (lane & 48) + i);   // edge i, this lane's head
            l += ai;
            acc += ai * bf2f(uf[i]);
        }
    }
    float res = (l > 0.f) ? acc / l : 0.f;
    out[(long)wid * HD + lane] = res + bias[lane];
}

extern "C" void kernel_launch(void* const* d_in, const int* in_sizes, int n_in,
                              void* d_out, int out_size, void* d_ws, size_t ws_size,
                              hipStream_t stream) {
    const float* feat      = (const float*)d_in[0];
    const float* edge_attr = (const float*)d_in[1];
    const int*   src       = (const int*)d_in[2];
    const int*   dst       = (const int*)d_in[3];
    const float* W_fc      = (const float*)d_in[4];
    const float* W_edge    = (const float*)d_in[5];
    const float* attn_h    = (const float*)d_in[6];
    const float* attn_t    = (const float*)d_in[7];
    const float* attn_e    = (const float*)d_in[8];
    const float* bias      = (const float*)d_in[9];
    float* out             = (float*)d_out;

    float* ws       = (float*)d_ws;
    float4* a4      = (float4*)ws;                     // E*4 floats = 12.8MB
    float4* eh4     = a4 + EE;                         // N*4
    float4* et4     = eh4 + NN;                        // N*4
    u16*   feat_bf  = (u16*)(et4 + NN);                // N*64 u16 = 6.4MB
    float* Wt       = (float*)(feat_bf + (long)NN * HD);  // 8192
    float* w_ee     = Wt + HD * IND;                   // 128
    int*   perm     = (int*)(w_ee + NH * EDD);         // E
    int*   rank     = perm + EE;                       // E
    int*   ssrc     = rank + EE;                       // E
    int*   deg      = ssrc + EE;                       // N
    int*   offs     = deg + NN;                        // N
    int*   part     = offs + NN;                       // NBLK
    // total ~ 33 MB of d_ws

    k_init_prep<<<NBLK, 256, 0, stream>>>(deg, W_fc, W_edge, attn_e, Wt, w_ee);
    dim3 ngrid(NBLK, 2);
    k_node<<<ngrid, 256, 0, stream>>>(feat, Wt, attn_h, attn_t, feat_bf,
                                      (float2*)eh4, (float2*)et4);
    k_hist<<<(EE + 255) / 256, 256, 0, stream>>>(dst, deg, rank);
    k_scan1<<<NBLK, 256, 0, stream>>>(deg, offs, part);
    k_scan2<<<1, 256, 0, stream>>>(part);
    k_scan3<<<NBLK, 256, 0, stream>>>(offs, part);
    k_perm<<<(EE + 255) / 256, 256, 0, stream>>>(dst, rank, offs, perm);
    k_att<<<(EE + 255) / 256, 256, 0, stream>>>(edge_attr, src, dst, w_ee, eh4, et4,
                                                perm, a4, ssrc);
    k_reduce<<<(NN * 64 + 255) / 256, 256, 0, stream>>>(offs, deg, (const float*)a4,
                                                        ssrc, feat_bf, bias, out);
}